// Round 14
// baseline (2537.159 us; speedup 1.0000x reference)
//
#include <hip/hip_runtime.h>

// FCOS Revision_PRED refinement — 2-NODE graph (A -> B), no memset node.
// Round-13 differential: warm A node = 24.1us vs 16.8us in-kernel => each
// graph node boundary costs ~7us here. So: every scratch byte is written
// unconditionally every call (no zero-init, no cross-call state):
//  - cand2[sy][c]: per-(split,column) TOP-1 packed key, or 0. Exact merge:
//    if every split's candidate count <=1, union of top-1s == all candidates
//    => top-9 of top-1s is exact. Any count>=2 (rare: two rows >0.5 within
//    one 16-row split hitting the same column) -> exact column rescan of ious.
//  - key = (val_bits<<32) | ((~r & 0xFFFF)<<8) | min(count,255): ordering is
//    (value desc, row asc); count byte can't flip order (row field dominates;
//    splits have disjoint rows so equal-value cross-split row ties impossible).
//    Assumes n1 <= 65535 (here 8192).
//  - rowany[sy][bxi]: per-(split,block) 32-bit row mask (rps<=32) -> missing.
// Measured facts: A at 8 TB/s store ceiling (r9); grid.sync ~100us (r11);
// B ILP-batching worth ~5us (r12). Numerics: bulk rcp+Newton (<=2ulp);
// >0.499999 recomputed __fdiv_rn (everything near/above 0.5 bit-exact vs
// numpy); __f*_rn blocks FMA contraction.
//
// Outputs (flat float32, in return order):
//   [0, N2*4)              refined_boxes [N2,4]
//   [N2*4, N2*5)           s2            [N2]
//   [N2*5, N2*6)           c2            [N2] (int -> float)
//   [N2*6, N2*6+N1)        missing_mask  [N1] (bool -> 0/1)
//   [N2*6+N1, ...)         ious          [N1,N2]

constexpr int TOPK = 9;  // up to 8 suppressions + final winner

__device__ __forceinline__ void key_insert(unsigned long long (&t)[TOPK],
                                           unsigned long long pk) {
    if (pk > t[TOPK - 1]) {
#pragma unroll
        for (int j = TOPK - 1; j >= 0; --j) {
            const bool gt_cur  = pk > t[j];
            const bool gt_prev = (j > 0) ? (pk > t[j - 1]) : false;
            if (gt_cur) t[j] = gt_prev ? t[j - 1] : pk;
        }
    }
}

// ---------------------------------------------------------------------------
// Kernel A: IoU matrix (4 cols/thread, float4 stores) + per-(split,column)
// top-1 key + count + per-(split,block) row mask. Everything written
// unconditionally. grid = (bx, S); rps rows per split (<=32).
// ---------------------------------------------------------------------------
__global__ __launch_bounds__(256) void iou_top1_kernel(
    const float* __restrict__ b1, const float* __restrict__ b2,
    float* __restrict__ ious,
    unsigned long long* __restrict__ cand2, unsigned int* __restrict__ rowany,
    int n1, int n2, int rps, int bx)
{
    const int bxi = blockIdx.x;
    const int sy  = blockIdx.y;
    const int c0  = (bxi * (int)blockDim.x + (int)threadIdx.x) * 4;
    __shared__ unsigned int blk_rowmask;
    if (threadIdx.x == 0) blk_rowmask = 0u;
    __syncthreads();

    unsigned int rowmask = 0u;
    unsigned long long best[4] = {0ull, 0ull, 0ull, 0ull};
    unsigned int cntk[4] = {0u, 0u, 0u, 0u};

    if (c0 < n2) {
        const int r0 = sy * rps;
        const int r1 = min(r0 + rps, n1);

        float4 bxv[4]; float ar[4];
#pragma unroll
        for (int k = 0; k < 4; ++k) {
            bxv[k] = reinterpret_cast<const float4*>(b2)[c0 + k];
            ar[k] = __fmul_rn(__fsub_rn(bxv[k].z, bxv[k].x),
                              __fsub_rn(bxv[k].w, bxv[k].y));
        }

        float* orow = ious + (size_t)r0 * n2 + c0;
        for (int r = r0; r < r1; ++r, orow += n2) {
            const float4 p = reinterpret_cast<const float4*>(b1)[r]; // uniform
            const float a1 = __fmul_rn(__fsub_rn(p.z, p.x),
                                       __fsub_rn(p.w, p.y));
            float v[4], ovs[4], uns[4];
#pragma unroll
            for (int k = 0; k < 4; ++k) {
                const float wx = fmaxf(__fsub_rn(fminf(p.z, bxv[k].z),
                                                 fmaxf(p.x, bxv[k].x)), 0.0f);
                const float wy = fmaxf(__fsub_rn(fminf(p.w, bxv[k].w),
                                                 fmaxf(p.y, bxv[k].y)), 0.0f);
                const float ov = __fmul_rn(wx, wy);
                const float un = fmaxf(__fsub_rn(__fadd_rn(a1, ar[k]), ov),
                                       1e-6f);
                ovs[k] = ov; uns[k] = un;
                float rc = __builtin_amdgcn_rcpf(un);
                rc = rc * fmaf(-un, rc, 2.0f);    // 1 Newton step, <=2 ulp
                v[k] = ov * rc;
            }

            // near-threshold: exact recompute + candidate/rowmask updates.
            // 0.499999 is ~17 ulps below 0.5 (covers the <=2ulp NR band).
            const float vmax = fmaxf(fmaxf(v[0], v[1]), fmaxf(v[2], v[3]));
            if (vmax > 0.499999f) {                // rare wave branch
#pragma unroll
                for (int k = 0; k < 4; ++k) {
                    if (v[k] > 0.499999f) {
                        const float ve = __fdiv_rn(ovs[k], uns[k]);
                        v[k] = ve;
                        if (ve >= 0.5f) {
                            rowmask |= 1u << (r - r0);
                            if (ve > 0.5f) {
                                cntk[k] += 1u;
                                const unsigned long long key =
                                    ((unsigned long long)__float_as_uint(ve) << 32)
                                  | ((unsigned long long)
                                        ((~(unsigned int)r) & 0xFFFFu) << 8);
                                if (key > best[k]) best[k] = key;
                            }
                        }
                    }
                }
            }
            *reinterpret_cast<float4*>(orow) =
                make_float4(v[0], v[1], v[2], v[3]);
        }

        // finalize count byte; write unconditionally (0 = no candidate)
        unsigned long long* dst = cand2 + (size_t)sy * n2 + c0;
#pragma unroll
        for (int k = 0; k < 4; ++k) {
            if (best[k]) best[k] |= (unsigned long long)min(cntk[k], 255u);
            dst[k] = best[k];
        }
    }

    atomicOr(&blk_rowmask, rowmask);               // LDS atomic
    __syncthreads();
    if (threadIdx.x == 0)
        rowany[sy * bx + bxi] = blk_rowmask;       // unconditional
}

// ---------------------------------------------------------------------------
// Kernel B (fused refine + missing): per column, top-9 merge of per-split
// top-1 keys (4-wide ILP, coalesced); any split-count>=2 -> exact column
// rescan of ious. Then simulate <=8 suppressions, scatter the 0.5s, write
// boxes/scores/classes; threads in [0,n1) also write missing_mask.
// ---------------------------------------------------------------------------
__global__ __launch_bounds__(256) void refine_missing_kernel(
    const float* __restrict__ b1, const float* __restrict__ s1,
    const int* __restrict__ c1,
    const float* __restrict__ b2, const float* __restrict__ s2,
    const int* __restrict__ c2,
    const unsigned long long* __restrict__ cand2,
    const unsigned int* __restrict__ rowany,
    float* __restrict__ out_boxes, float* __restrict__ out_s,
    float* __restrict__ out_c, float* __restrict__ out_m,
    float* __restrict__ ious,
    int n1, int n2, int S, int rps, int bx)
{
    const int tid = blockIdx.x * blockDim.x + threadIdx.x;

    if (tid < n1) {                                 // missing_mask part
        const int sy  = tid / rps;
        const int bit = tid - sy * rps;
        unsigned int m = 0u;
        for (int x = 0; x < bx; ++x) m |= rowany[sy * bx + x];
        out_m[tid] = ((m >> bit) & 1u) ? 0.0f : 1.0f;
    }

    const int c = tid;
    if (c >= n2) return;

    const float s2c = s2[c];                        // hoisted

    unsigned long long t[TOPK];
#pragma unroll
    for (int j = 0; j < TOPK; ++j) t[j] = 0ull;     // 0 < any valid key

    bool rescan = false;
    {
        const unsigned long long* L = cand2 + c;    // coalesced across lanes
        int sy = 0;
        for (; sy + 4 <= S; sy += 4) {              // 4 independent loads/iter
            const unsigned long long p0 = L[(size_t)(sy + 0) * n2];
            const unsigned long long p1 = L[(size_t)(sy + 1) * n2];
            const unsigned long long p2 = L[(size_t)(sy + 2) * n2];
            const unsigned long long p3 = L[(size_t)(sy + 3) * n2];
            rescan |= ((p0 & 0xFFull) > 1ull) | ((p1 & 0xFFull) > 1ull)
                    | ((p2 & 0xFFull) > 1ull) | ((p3 & 0xFFull) > 1ull);
            key_insert(t, p0); key_insert(t, p1);
            key_insert(t, p2); key_insert(t, p3);
        }
        for (; sy < S; ++sy) {
            const unsigned long long pk = L[(size_t)sy * n2];
            rescan |= ((pk & 0xFFull) > 1ull);
            key_insert(t, pk);
        }
    }

    if (rescan) {                                   // exact fallback (rare)
#pragma unroll
        for (int j = 0; j < TOPK; ++j) t[j] = 0ull;
        for (int r = 0; r < n1; ++r) {
            const float v = ious[(size_t)r * n2 + c];
            if (v > 0.5f)
                key_insert(t, ((unsigned long long)__float_as_uint(v) << 32)
                            | (unsigned long long)(~(unsigned int)r));
        }
    }

    int m = 0;
#pragma unroll
    for (int j = 0; j < TOPK; ++j) m += (t[j] != 0ull) ? 1 : 0;

    int   ti[TOPK];
    float s1v[TOPK];
#pragma unroll
    for (int j = 0; j < TOPK; ++j) {
        ti[j] = rescan
            ? (int)(~(unsigned int)(t[j] & 0xFFFFFFFFull))
            : (int)((~(unsigned int)(t[j] >> 8)) & 0xFFFFu);
        s1v[j] = (j < m) ? s1[ti[j]] : 0.0f;        // independent gathers
    }

    // k = length of maximal prefix with scores1 < scores2 (suppressed), cap 8
    int k = 0;
#pragma unroll
    for (int j = 0; j < 8; ++j)
        if (j < m && k == j && s1v[j] < s2c) k = j + 1;

    // scatter the suppressions (entries replaced by exactly 0.5)
#pragma unroll
    for (int j = 0; j < 8; ++j)
        if (j < k) ious[(size_t)ti[j] * n2 + c] = 0.5f;

    const bool refine = (k < m);
    int winner = 0; float wsc = 0.0f;
#pragma unroll
    for (int j = 0; j < TOPK; ++j)
        if (j == k) { winner = ti[j]; wsc = s1v[j]; }

    float4 ob; float os, oc;
    if (refine) {
        ob = reinterpret_cast<const float4*>(b1)[winner];
        os = wsc;
        oc = (float)c1[winner];
    } else {
        ob = reinterpret_cast<const float4*>(b2)[c];
        os = s2c;
        oc = (float)c2[c];
    }
    ob.x = fmaxf(ob.x, 0.0f); ob.y = fmaxf(ob.y, 0.0f);   // (b+|b|)*0.5
    ob.z = fmaxf(ob.z, 0.0f); ob.w = fmaxf(ob.w, 0.0f);
    reinterpret_cast<float4*>(out_boxes)[c] = ob;
    out_s[c] = os;
    out_c[c] = oc;
}

extern "C" void kernel_launch(void* const* d_in, const int* in_sizes, int n_in,
                              void* d_out, int out_size, void* d_ws, size_t ws_size,
                              hipStream_t stream) {
    (void)n_in; (void)out_size;
    const float* b1 = (const float*)d_in[0];
    const float* s1 = (const float*)d_in[1];
    const int*   c1 = (const int*)d_in[2];
    const float* b2 = (const float*)d_in[3];
    const float* s2 = (const float*)d_in[4];
    const int*   c2 = (const int*)d_in[5];
    const int n1 = in_sizes[1];   // 8192 (must be <= 65535 for key packing)
    const int n2 = in_sizes[4];   // 4096

    float* out       = (float*)d_out;
    float* out_boxes = out;
    float* out_s     = out + (size_t)n2 * 4;
    float* out_c     = out_s + n2;
    float* out_m     = out_c + n2;
    float* out_ious  = out_m + n1;

    const int bx = (n2 / 4 + 255) / 256;           // 4 at n2=4096
    int rps = 16;                                  // rows per split (<=32)
    int S   = (n1 + rps - 1) / rps;                // 512
    // ws: [cand2: S*n2 u64][rowany: S*bx u32] — all written every call
    while (rps < 32 &&
           (size_t)S * n2 * 8 + (size_t)S * bx * 4 > ws_size) {
        rps <<= 1; S = (n1 + rps - 1) / rps;
    }
    unsigned long long* cand2  = (unsigned long long*)d_ws;
    unsigned int*       rowany =
        (unsigned int*)((char*)d_ws + (size_t)S * n2 * 8);

    dim3 gridA(bx, S);
    iou_top1_kernel<<<gridA, 256, 0, stream>>>(b1, b2, out_ious, cand2,
                                               rowany, n1, n2, rps, bx);
    const int ntot = max(n1, n2);
    refine_missing_kernel<<<(ntot + 255) / 256, 256, 0, stream>>>(
        b1, s1, c1, b2, s2, c2, cand2, rowany,
        out_boxes, out_s, out_c, out_m, out_ious, n1, n2, S, rps, bx);
}

// Round 15
// 46.484 us; speedup vs baseline: 54.5810x; 54.5810x over previous
//
#include <hip/hip_runtime.h>

// FCOS Revision_PRED refinement — round-12 verified optimum (46.2us), exact
// revert. 3-dispatch graph: memset(24KB) -> IoU+candidates -> refine+missing.
//
// Evidence ledger (why this structure is final):
//  - A at measured 8 TB/s store ceiling: 134MB/16.8us marginal pass (r9).
//  - node boundary ~7us after 134MB dirty (r13 differential 24.1 vs 16.8).
//  - cooperative grid.sync ~100us/sync on 8 XCDs -> fusion worse (r11: 230us).
//  - top1-per-split 2-node scheme: fallback fires on ~57% of columns (r14:
//    2537us) -> atomic append lists + zeroed cnt are load-bearing.
//  - nt stores / row-linear sweeps / occupancy: all null (r6-r8).
//  - B 4-wide ILP batched candidate loads: -4.7us (r12).
// Numerics: bulk rcp+Newton (<=2ulp); any value > 0.499999 recomputed with
// __fdiv_rn -> everything participating in selection is bit-exact vs numpy;
// __f*_rn blocks FMA contraction in un.
//
// Outputs (flat float32, in return order):
//   [0, N2*4)              refined_boxes [N2,4]
//   [N2*4, N2*5)           s2            [N2]
//   [N2*5, N2*6)           c2            [N2] (int -> float)
//   [N2*6, N2*6+N1)        missing_mask  [N1] (bool -> 0/1)
//   [N2*6+N1, ...)         ious          [N1,N2]

constexpr int TOPK = 9;  // up to 8 suppressions + final winner

__device__ __forceinline__ void key_insert(unsigned long long (&t)[TOPK],
                                           unsigned long long pk) {
    if (pk > t[TOPK - 1]) {
#pragma unroll
        for (int j = TOPK - 1; j >= 0; --j) {
            const bool gt_cur  = pk > t[j];
            const bool gt_prev = (j > 0) ? (pk > t[j - 1]) : false;
            if (gt_cur) t[j] = gt_prev ? t[j - 1] : pk;
        }
    }
}

// ---------------------------------------------------------------------------
// Kernel A: IoU matrix (4 cols/thread, float4 stores) + rare candidate
// append (e-major) + row flags. blockIdx.y = row split.
// ---------------------------------------------------------------------------
__global__ __launch_bounds__(256) void iou_cand_kernel(
    const float* __restrict__ b1, const float* __restrict__ b2,
    float* __restrict__ ious,
    unsigned int* __restrict__ cnt, unsigned long long* __restrict__ cand,
    unsigned char* __restrict__ rowflag,
    int n1, int n2, int rps, int cap)
{
    const int tid = blockIdx.x * blockDim.x + threadIdx.x;
    const int c0 = tid * 4;
    if (c0 >= n2) return;
    const int r0 = blockIdx.y * rps;
    const int r1 = min(r0 + rps, n1);

    float4 bxv[4]; float ar[4];
#pragma unroll
    for (int k = 0; k < 4; ++k) {
        bxv[k] = reinterpret_cast<const float4*>(b2)[c0 + k];
        ar[k] = __fmul_rn(__fsub_rn(bxv[k].z, bxv[k].x),
                          __fsub_rn(bxv[k].w, bxv[k].y));
    }

    float* orow = ious + (size_t)r0 * n2 + c0;
    for (int r = r0; r < r1; ++r, orow += n2) {
        const float4 p = reinterpret_cast<const float4*>(b1)[r];  // uniform
        const float a1 = __fmul_rn(__fsub_rn(p.z, p.x), __fsub_rn(p.w, p.y));
        float v[4], ovs[4], uns[4];
#pragma unroll
        for (int k = 0; k < 4; ++k) {
            const float wx = fmaxf(__fsub_rn(fminf(p.z, bxv[k].z),
                                             fmaxf(p.x, bxv[k].x)), 0.0f);
            const float wy = fmaxf(__fsub_rn(fminf(p.w, bxv[k].w),
                                             fmaxf(p.y, bxv[k].y)), 0.0f);
            const float ov = __fmul_rn(wx, wy);
            const float un = fmaxf(__fsub_rn(__fadd_rn(a1, ar[k]), ov), 1e-6f);
            ovs[k] = ov; uns[k] = un;
            float rc = __builtin_amdgcn_rcpf(un);
            rc = rc * fmaf(-un, rc, 2.0f);        // 1 Newton step, <=2 ulp
            v[k] = ov * rc;
        }

        // near-threshold: exact recompute + side effects.
        // 0.499999 is ~17 ulps below 0.5 (covers the <=2ulp NR band).
        const float vmax = fmaxf(fmaxf(v[0], v[1]), fmaxf(v[2], v[3]));
        if (vmax > 0.499999f) {                    // rare wave branch
#pragma unroll
            for (int k = 0; k < 4; ++k) {
                if (v[k] > 0.499999f) {
                    const float ve = __fdiv_rn(ovs[k], uns[k]);
                    v[k] = ve;
                    if (ve >= 0.5f) {
                        rowflag[r] = 1;
                        if (ve > 0.5f) {
                            const unsigned int idx = atomicAdd(&cnt[c0 + k], 1u);
                            if (idx < (unsigned int)cap)
                                // (value desc, row asc) key: ties ->
                                // smaller r wins, as jnp.argmax.
                                cand[(size_t)idx * n2 + (c0 + k)] =
                                    ((unsigned long long)__float_as_uint(ve) << 32)
                                  | (unsigned long long)(~(unsigned int)r);
                        }
                    }
                }
            }
        }
        *reinterpret_cast<float4*>(orow) = make_float4(v[0], v[1], v[2], v[3]);
    }
}

// ---------------------------------------------------------------------------
// Kernel B (fused refine + missing): per column, top-9 from the candidate
// list with 4-wide ILP-batched loads (top-9 of a multiset is insertion-
// order-invariant -> batching preserves semantics), simulate <=8
// suppressions, scatter the 0.5s, write boxes/scores/classes; threads in
// [0,n1) also write missing_mask. Overflow (cnt > cap): rescan column.
// ---------------------------------------------------------------------------
__global__ __launch_bounds__(64) void refine_missing_kernel(
    const float* __restrict__ b1, const float* __restrict__ s1,
    const int* __restrict__ c1,
    const float* __restrict__ b2, const float* __restrict__ s2,
    const int* __restrict__ c2,
    const unsigned int* __restrict__ cnt,
    const unsigned long long* __restrict__ cand,
    const unsigned char* __restrict__ rowflag,
    float* __restrict__ out_boxes, float* __restrict__ out_s,
    float* __restrict__ out_c, float* __restrict__ out_m,
    float* __restrict__ ious,
    int n1, int n2, int cap)
{
    const int tid = blockIdx.x * blockDim.x + threadIdx.x;

    if (tid < n1)                                   // missing_mask part
        out_m[tid] = rowflag[tid] ? 0.0f : 1.0f;

    const int c = tid;
    if (c >= n2) return;

    const float s2c = s2[c];                        // hoisted

    unsigned long long t[TOPK];
#pragma unroll
    for (int j = 0; j < TOPK; ++j) t[j] = 0ull;     // 0 < any valid key

    const int n = (int)cnt[c];
    if (n <= cap) {
        const unsigned long long* L = cand + c;     // e-major: coalesced
        int e = 0;
        for (; e + 4 <= n; e += 4) {                // 4 independent loads/iter
            const unsigned long long p0 = L[(size_t)(e + 0) * n2];
            const unsigned long long p1 = L[(size_t)(e + 1) * n2];
            const unsigned long long p2 = L[(size_t)(e + 2) * n2];
            const unsigned long long p3 = L[(size_t)(e + 3) * n2];
            key_insert(t, p0); key_insert(t, p1);
            key_insert(t, p2); key_insert(t, p3);
        }
        for (; e < n; ++e)
            key_insert(t, L[(size_t)e * n2]);
    } else {                                        // overflow: rescan column
        for (int r = 0; r < n1; ++r) {
            const float v = ious[(size_t)r * n2 + c];
            if (v > 0.5f)
                key_insert(t, ((unsigned long long)__float_as_uint(v) << 32)
                            | (unsigned long long)(~(unsigned int)r));
        }
    }

    int m = 0;
#pragma unroll
    for (int j = 0; j < TOPK; ++j) m += (t[j] != 0ull) ? 1 : 0;

    int   ti[TOPK];
    float s1v[TOPK];
#pragma unroll
    for (int j = 0; j < TOPK; ++j) {
        ti[j]  = (int)~(unsigned int)(t[j] & 0xffffffffull);
        s1v[j] = (j < m) ? s1[ti[j]] : 0.0f;        // independent gathers
    }

    // k = length of maximal prefix with scores1 < scores2 (suppressed), cap 8
    int k = 0;
#pragma unroll
    for (int j = 0; j < 8; ++j)
        if (j < m && k == j && s1v[j] < s2c) k = j + 1;

    // scatter the suppressions (entries replaced by exactly 0.5)
#pragma unroll
    for (int j = 0; j < 8; ++j)
        if (j < k) ious[(size_t)ti[j] * n2 + c] = 0.5f;

    const bool refine = (k < m);
    int winner = 0; float wsc = 0.0f;
#pragma unroll
    for (int j = 0; j < TOPK; ++j)
        if (j == k) { winner = ti[j]; wsc = s1v[j]; }

    float4 ob; float os, oc;
    if (refine) {
        ob = reinterpret_cast<const float4*>(b1)[winner];
        os = wsc;
        oc = (float)c1[winner];
    } else {
        ob = reinterpret_cast<const float4*>(b2)[c];
        os = s2c;
        oc = (float)c2[c];
    }
    ob.x = fmaxf(ob.x, 0.0f); ob.y = fmaxf(ob.y, 0.0f);   // (b+|b|)*0.5
    ob.z = fmaxf(ob.z, 0.0f); ob.w = fmaxf(ob.w, 0.0f);
    reinterpret_cast<float4*>(out_boxes)[c] = ob;
    out_s[c] = os;
    out_c[c] = oc;
}

extern "C" void kernel_launch(void* const* d_in, const int* in_sizes, int n_in,
                              void* d_out, int out_size, void* d_ws, size_t ws_size,
                              hipStream_t stream) {
    (void)n_in; (void)out_size;
    const float* b1 = (const float*)d_in[0];
    const float* s1 = (const float*)d_in[1];
    const int*   c1 = (const int*)d_in[2];
    const float* b2 = (const float*)d_in[3];
    const float* s2 = (const float*)d_in[4];
    const int*   c2 = (const int*)d_in[5];
    const int n1 = in_sizes[1];   // 8192
    const int n2 = in_sizes[4];   // 4096

    float* out       = (float*)d_out;
    float* out_boxes = out;
    float* out_s     = out + (size_t)n2 * 4;
    float* out_c     = out_s + n2;
    float* out_m     = out_c + n2;
    float* out_ious  = out_m + n1;

    // ws: [cnt: n2 u32][rowflag: n1 u8][cand: cap*n2 u64, e-major]
    const size_t cnt_b    = (size_t)n2 * sizeof(unsigned int);
    const size_t flag_b   = (size_t)n1;
    const size_t cand_off = (cnt_b + flag_b + 15) & ~(size_t)15;
    int cap = 1024;                                // overflow path covers rest
    while (cap > 16 && cand_off + (size_t)cap * n2 * 8 > ws_size) cap >>= 1;
    unsigned int*       cnt     = (unsigned int*)d_ws;
    unsigned char*      rowflag = (unsigned char*)d_ws + cnt_b;
    unsigned long long* cand    = (unsigned long long*)((char*)d_ws + cand_off);

    (void)hipMemsetAsync(d_ws, 0, cnt_b + flag_b, stream);

    const int bx = (n2 / 4 + 255) / 256;           // 4 at n2=4096
    int S = 2048 / bx; if (S < 1) S = 1; if (S > n1) S = n1;   // 512 splits
    const int rps = (n1 + S - 1) / S;              // 16 rows/block

    dim3 gridA(bx, S);
    iou_cand_kernel<<<gridA, 256, 0, stream>>>(b1, b2, out_ious, cnt, cand,
                                               rowflag, n1, n2, rps, cap);
    const int ntot = max(n1, n2);
    refine_missing_kernel<<<(ntot + 63) / 64, 64, 0, stream>>>(
        b1, s1, c1, b2, s2, c2, cnt, cand, rowflag,
        out_boxes, out_s, out_c, out_m, out_ious, n1, n2, cap);
}